// Round 2
// baseline (5166.390 us; speedup 1.0000x reference)
//
#include <hip/hip_runtime.h>
#include <hip/hip_bf16.h>
#include <cstdint>
#include <cstddef>

#define BB   16
#define NN   4096
#define DD   128
#define SS   1024
#define CIN  131
#define C1   256
#define MM   (SS*16)       // 16384 rows per batch

__device__ __forceinline__ float bf2f(unsigned short u) {
  union { unsigned int i; float f; } x; x.i = ((unsigned int)u) << 16; return x.f;
}
__device__ __forceinline__ unsigned short f2bf(float f) {
  __hip_bfloat16 h = __float2bfloat16(f);
  union { __hip_bfloat16 h; unsigned short u; } c; c.h = h; return c.u;
}

// ---------------- FPS: one workgroup per batch ----------------
__global__ __launch_bounds__(256) void fps_kernel(
    const float* __restrict__ xyz, float* __restrict__ out_xyz)
{
  __shared__ float xs[NN], ys[NN], zs[NN];
  __shared__ float rv[4];
  __shared__ int   ri[4];
  __shared__ int   sfar;
  const int b = blockIdx.x;
  const int tid = threadIdx.x;
  const float* base = xyz + (size_t)b * NN * 3;
  for (int i = tid; i < NN; i += 256) {
    xs[i] = base[i*3+0]; ys[i] = base[i*3+1]; zs[i] = base[i*3+2];
  }
  __syncthreads();
  float mind[16];
  #pragma unroll
  for (int j = 0; j < 16; ++j) mind[j] = 1e10f;
  int far = 0;
  for (int it = 0; it < SS; ++it) {
    if (tid == 0) {
      out_xyz[(b*SS + it)*3 + 0] = xs[far];
      out_xyz[(b*SS + it)*3 + 1] = ys[far];
      out_xyz[(b*SS + it)*3 + 2] = zs[far];
    }
    const float cx = xs[far], cy = ys[far], cz = zs[far];
    float bv = -1.0f; int bi = 0x7fffffff;
    #pragma unroll
    for (int j = 0; j < 16; ++j) {
      const int p = j*256 + tid;
      float dx = __fsub_rn(xs[p], cx);
      float dy = __fsub_rn(ys[p], cy);
      float dz = __fsub_rn(zs[p], cz);
      float d  = __fadd_rn(__fadd_rn(__fmul_rn(dx,dx), __fmul_rn(dy,dy)), __fmul_rn(dz,dz));
      float md = fminf(mind[j], d);
      mind[j] = md;
      if (md > bv || (md == bv && p < bi)) { bv = md; bi = p; }
    }
    #pragma unroll
    for (int off = 32; off > 0; off >>= 1) {
      float ov = __shfl_down(bv, off);
      int   oi = __shfl_down(bi, off);
      if (ov > bv || (ov == bv && oi < bi)) { bv = ov; bi = oi; }
    }
    if ((tid & 63) == 0) { rv[tid>>6] = bv; ri[tid>>6] = bi; }
    __syncthreads();
    if (tid == 0) {
      float fv = rv[0]; int fi = ri[0];
      #pragma unroll
      for (int w = 1; w < 4; ++w)
        if (rv[w] > fv || (rv[w] == fv && ri[w] < fi)) { fv = rv[w]; fi = ri[w]; }
      sfar = fi;
    }
    __syncthreads();
    far = sfar;
  }
}

// ---------------- kNN: one thread per (b,s), top-16 insertion sort ----------------
__global__ __launch_bounds__(256) void knn_kernel(
    const float* __restrict__ xyz, const float* __restrict__ new_xyz, int* __restrict__ knn_idx)
{
  __shared__ float tx_[512], ty_[512], tz_[512];
  const int blk = blockIdx.x;
  const int b = blk >> 2;
  const int s = ((blk & 3) << 8) + threadIdx.x;
  const float cx = new_xyz[((b<<10)+s)*3+0];
  const float cy = new_xyz[((b<<10)+s)*3+1];
  const float cz = new_xyz[((b<<10)+s)*3+2];
  float td[16]; int ti[16];
  #pragma unroll
  for (int j = 0; j < 16; ++j) { td[j] = 3.4e38f; ti[j] = 0; }
  const float* base = xyz + (size_t)b*NN*3;
  for (int t0 = 0; t0 < NN; t0 += 512) {
    __syncthreads();
    for (int i = threadIdx.x; i < 512; i += 256) {
      tx_[i] = base[(t0+i)*3+0]; ty_[i] = base[(t0+i)*3+1]; tz_[i] = base[(t0+i)*3+2];
    }
    __syncthreads();
    for (int i = 0; i < 512; ++i) {
      float dx = __fsub_rn(tx_[i], cx);
      float dy = __fsub_rn(ty_[i], cy);
      float dz = __fsub_rn(tz_[i], cz);
      float d  = __fadd_rn(__fadd_rn(__fmul_rn(dx,dx), __fmul_rn(dy,dy)), __fmul_rn(dz,dz));
      if (d < td[15]) {
        td[15] = d; ti[15] = t0 + i;
        #pragma unroll
        for (int j = 15; j > 0; --j) {
          if (td[j] < td[j-1]) {
            float tf = td[j]; td[j] = td[j-1]; td[j-1] = tf;
            int   tt = ti[j]; ti[j] = ti[j-1]; ti[j-1] = tt;
          }
        }
      }
    }
  }
  int* o = knn_idx + ((size_t)((b<<10)+s))*16;
  #pragma unroll
  for (int j = 0; j < 16; ++j) o[j] = ti[j];
}

// ---------------- pass A: y1 tile compute, BN1 partials only ----------------
__global__ __launch_bounds__(256) void gemm1_stats_kernel(
    const float* __restrict__ xyz, const float* __restrict__ points,
    const float* __restrict__ W1, const float* __restrict__ bias1,
    const int* __restrict__ knn_idx, const float* __restrict__ new_xyz,
    float* __restrict__ Psum, float* __restrict__ Psq)
{
  __shared__ unsigned short Fs[131][64];
  __shared__ unsigned short Ws[66][64];
  __shared__ float Red[2][16][64];
  const int bx = blockIdx.x;   // n tile 0..3
  const int by = blockIdx.y;   // m tile 0..255
  const int b  = blockIdx.z;
  const int tid = threadIdx.x;
  const int tx = tid & 15, ty = tid >> 4;
  const int rg = tid >> 2, cg = tid & 3;

  const int m   = by*64 + rg;
  const int s   = m >> 4;
  const int kk_ = m & 15;
  const int p   = knn_idx[((b<<10)+s)*16 + kk_];
  const float* pbase = points + ((size_t)b*NN + p) * DD;
  float c3[3];
  c3[0] = xyz[((size_t)b*NN + p)*3+0] - new_xyz[((b<<10)+s)*3+0];
  c3[1] = xyz[((size_t)b*NN + p)*3+1] - new_xyz[((b<<10)+s)*3+1];
  c3[2] = xyz[((size_t)b*NN + p)*3+2] - new_xyz[((b<<10)+s)*3+2];
  for (int c = cg; c < CIN; c += 4) {
    float v = (c < 3) ? c3[c] : pbase[c-3];
    Fs[c][rg] = f2bf(v);
  }
  const int n_row = bx*64 + rg;

  float acc[4][4];
  #pragma unroll
  for (int i = 0; i < 4; ++i)
    #pragma unroll
    for (int j = 0; j < 4; ++j) acc[i][j] = 0.0f;

  for (int kc = 0; kc < 2; ++kc) {
    const int c0  = kc * 66;
    const int cnt = kc ? 65 : 66;
    __syncthreads();
    for (int c = cg; c < cnt; c += 4) Ws[c][rg] = f2bf(W1[n_row*CIN + c0 + c]);
    __syncthreads();
    for (int kk = 0; kk < cnt; ++kk) {
      ushort4 au = *(const ushort4*)&Fs[c0+kk][ty*4];
      ushort4 wu = *(const ushort4*)&Ws[kk][tx*4];
      float a0 = bf2f(au.x), a1 = bf2f(au.y), a2 = bf2f(au.z), a3 = bf2f(au.w);
      float w0 = bf2f(wu.x), w1 = bf2f(wu.y), w2 = bf2f(wu.z), w3 = bf2f(wu.w);
      acc[0][0] += a0*w0; acc[0][1] += a0*w1; acc[0][2] += a0*w2; acc[0][3] += a0*w3;
      acc[1][0] += a1*w0; acc[1][1] += a1*w1; acc[1][2] += a1*w2; acc[1][3] += a1*w3;
      acc[2][0] += a2*w0; acc[2][1] += a2*w1; acc[2][2] += a2*w2; acc[2][3] += a2*w3;
      acc[3][0] += a3*w0; acc[3][1] += a3*w1; acc[3][2] += a3*w2; acc[3][3] += a3*w3;
    }
  }

  float ps[4] = {0,0,0,0}, pq[4] = {0,0,0,0};
  #pragma unroll
  for (int j = 0; j < 4; ++j) {
    const float bias = bias1[bx*64 + tx*4 + j];
    #pragma unroll
    for (int i = 0; i < 4; ++i) {
      float yv = acc[i][j] + bias;
      ps[j] += yv; pq[j] += yv*yv;
    }
  }
  #pragma unroll
  for (int j = 0; j < 4; ++j) { Red[0][ty][tx*4+j] = ps[j]; Red[1][ty][tx*4+j] = pq[j]; }
  __syncthreads();
  if (tid < 64) {
    float ssum = 0.f, ssq = 0.f;
    #pragma unroll
    for (int t = 0; t < 16; ++t) { ssum += Red[0][t][tid]; ssq += Red[1][t][tid]; }
    const int ch  = bx*64 + tid;
    const int row = b*256 + by;
    Psum[ch*4096 + row] = ssum;
    Psq [ch*4096 + row] = ssq;
  }
}

// ---------------- stats: per-channel mean/var -> scale/shift ----------------
__global__ __launch_bounds__(256) void stats_kernel(
    const float* __restrict__ Psum, const float* __restrict__ Psq,
    const float* __restrict__ gamma, const float* __restrict__ beta,
    float* __restrict__ scale, float* __restrict__ shift)
{
  __shared__ float sv[4], qv[4];
  const int c = blockIdx.x, tid = threadIdx.x;
  float s = 0.f, q = 0.f;
  for (int r = tid; r < 4096; r += 256) { s += Psum[c*4096+r]; q += Psq[c*4096+r]; }
  #pragma unroll
  for (int off = 32; off > 0; off >>= 1) { s += __shfl_down(s, off); q += __shfl_down(q, off); }
  if ((tid & 63) == 0) { sv[tid>>6] = s; qv[tid>>6] = q; }
  __syncthreads();
  if (tid == 0) {
    s = sv[0]+sv[1]+sv[2]+sv[3]; q = qv[0]+qv[1]+qv[2]+qv[3];
    const float count = 262144.0f;
    float mean = s / count;
    float var  = fmaxf(q / count - mean*mean, 0.0f);
    float inv  = 1.0f / sqrtf(var + 1e-5f);
    float sc   = gamma[c] * inv;
    scale[c] = sc;
    shift[c] = beta[c] - mean * sc;
  }
}

// ---------------- fused: recompute y1 tile -> bn1+relu (LDS) -> conv2 + BN2 partials + max/min over K ----------------
__global__ __launch_bounds__(256) void fused2_kernel(
    const float* __restrict__ xyz, const float* __restrict__ points,
    const float* __restrict__ W1, const float* __restrict__ bias1,
    const int* __restrict__ knn_idx, const float* __restrict__ new_xyz,
    const float* __restrict__ sc1v, const float* __restrict__ sh1v,
    const float* __restrict__ W2, const float* __restrict__ bias2,
    float* __restrict__ maxv, float* __restrict__ minv,
    float* __restrict__ Psum, float* __restrict__ Psq)
{
  __shared__ unsigned short Fs[131][64];   // feature tile [c][m], bf16
  __shared__ unsigned short Ws[66][64];    // weight chunk [k][n], bf16 (stage1+stage2)
  __shared__ unsigned short As[256][64];   // relu(bn1(y1)) [ch][m], bf16
  __shared__ float Red[16][64];
  const int by = blockIdx.x;   // m tile 0..255
  const int b  = blockIdx.y;
  const int tid = threadIdx.x;
  const int tx = tid & 15, ty = tid >> 4;
  const int rg = tid >> 2, cg = tid & 3;

  // ---- stage features (once) ----
  {
    const int m   = by*64 + rg;
    const int s   = m >> 4;
    const int kk_ = m & 15;
    const int p   = knn_idx[((b<<10)+s)*16 + kk_];
    const float* pbase = points + ((size_t)b*NN + p) * DD;
    float c3[3];
    c3[0] = xyz[((size_t)b*NN + p)*3+0] - new_xyz[((b<<10)+s)*3+0];
    c3[1] = xyz[((size_t)b*NN + p)*3+1] - new_xyz[((b<<10)+s)*3+1];
    c3[2] = xyz[((size_t)b*NN + p)*3+2] - new_xyz[((b<<10)+s)*3+2];
    for (int c = cg; c < CIN; c += 4) {
      float v = (c < 3) ? c3[c] : pbase[c-3];
      Fs[c][rg] = f2bf(v);
    }
  }

  // ---- stage 1: y1 = F @ W1^T ; A = relu(bn1(y1)) -> As ----
  for (int nc = 0; nc < 4; ++nc) {
    const int n0 = nc*64;
    float acc[4][4];
    #pragma unroll
    for (int i = 0; i < 4; ++i)
      #pragma unroll
      for (int j = 0; j < 4; ++j) acc[i][j] = 0.0f;
    for (int kc = 0; kc < 2; ++kc) {
      const int c0  = kc * 66;
      const int cnt = kc ? 65 : 66;
      __syncthreads();
      for (int c = cg; c < cnt; c += 4) Ws[c][rg] = f2bf(W1[(n0+rg)*CIN + c0 + c]);
      __syncthreads();
      for (int kk = 0; kk < cnt; ++kk) {
        ushort4 au = *(const ushort4*)&Fs[c0+kk][ty*4];
        ushort4 wu = *(const ushort4*)&Ws[kk][tx*4];
        float a0 = bf2f(au.x), a1 = bf2f(au.y), a2 = bf2f(au.z), a3 = bf2f(au.w);
        float w0 = bf2f(wu.x), w1 = bf2f(wu.y), w2 = bf2f(wu.z), w3 = bf2f(wu.w);
        acc[0][0] += a0*w0; acc[0][1] += a0*w1; acc[0][2] += a0*w2; acc[0][3] += a0*w3;
        acc[1][0] += a1*w0; acc[1][1] += a1*w1; acc[1][2] += a1*w2; acc[1][3] += a1*w3;
        acc[2][0] += a2*w0; acc[2][1] += a2*w1; acc[2][2] += a2*w2; acc[2][3] += a2*w3;
        acc[3][0] += a3*w0; acc[3][1] += a3*w1; acc[3][2] += a3*w2; acc[3][3] += a3*w3;
      }
    }
    #pragma unroll
    for (int j = 0; j < 4; ++j) {
      const int n = n0 + tx*4 + j;
      const float bias = bias1[n], sc = sc1v[n], sh = sh1v[n];
      ushort4 pk;
      pk.x = f2bf(fmaxf((acc[0][j]+bias)*sc + sh, 0.0f));
      pk.y = f2bf(fmaxf((acc[1][j]+bias)*sc + sh, 0.0f));
      pk.z = f2bf(fmaxf((acc[2][j]+bias)*sc + sh, 0.0f));
      pk.w = f2bf(fmaxf((acc[3][j]+bias)*sc + sh, 0.0f));
      *(ushort4*)&As[n][ty*4] = pk;
    }
  }

  // ---- stage 2: y2 = A @ W2^T ; partial sums + max/min over k ----
  for (int nc = 0; nc < 4; ++nc) {
    const int n0 = nc*64;
    float acc[4][4];
    #pragma unroll
    for (int i = 0; i < 4; ++i)
      #pragma unroll
      for (int j = 0; j < 4; ++j) acc[i][j] = 0.0f;
    for (int kc = 0; kc < 4; ++kc) {
      const int k0 = kc*64;
      __syncthreads();
      for (int kk2 = cg; kk2 < 64; kk2 += 4) Ws[kk2][rg] = f2bf(W2[(n0+rg)*C1 + k0 + kk2]);
      __syncthreads();
      for (int kk = 0; kk < 64; ++kk) {
        ushort4 au = *(const ushort4*)&As[k0+kk][ty*4];
        ushort4 wu = *(const ushort4*)&Ws[kk][tx*4];
        float a0 = bf2f(au.x), a1 = bf2f(au.y), a2 = bf2f(au.z), a3 = bf2f(au.w);
        float w0 = bf2f(wu.x), w1 = bf2f(wu.y), w2 = bf2f(wu.z), w3 = bf2f(wu.w);
        acc[0][0] += a0*w0; acc[0][1] += a0*w1; acc[0][2] += a0*w2; acc[0][3] += a0*w3;
        acc[1][0] += a1*w0; acc[1][1] += a1*w1; acc[1][2] += a1*w2; acc[1][3] += a1*w3;
        acc[2][0] += a2*w0; acc[2][1] += a2*w1; acc[2][2] += a2*w2; acc[2][3] += a2*w3;
        acc[3][0] += a3*w0; acc[3][1] += a3*w1; acc[3][2] += a3*w2; acc[3][3] += a3*w3;
      }
    }
    // epilogue: yv = acc + bias2
    float ps[4], pq[4], mx[4], mn[4];
    #pragma unroll
    for (int j = 0; j < 4; ++j) {
      const float bias = bias2[n0 + tx*4 + j];
      float y0 = acc[0][j] + bias, y1_ = acc[1][j] + bias, y2_ = acc[2][j] + bias, y3 = acc[3][j] + bias;
      ps[j] = ((y0 + y1_) + y2_) + y3;
      pq[j] = ((y0*y0 + y1_*y1_) + y2_*y2_) + y3*y3;
      mx[j] = fmaxf(fmaxf(y0, y1_), fmaxf(y2_, y3));
      mn[j] = fminf(fminf(y0, y1_), fminf(y2_, y3));
    }
    const int row = b*256 + by;
    // round 1: sum
    __syncthreads();
    #pragma unroll
    for (int j = 0; j < 4; ++j) Red[ty][tx*4+j] = ps[j];
    __syncthreads();
    if (tid < 64) {
      float v = 0.f;
      #pragma unroll
      for (int t = 0; t < 16; ++t) v += Red[t][tid];
      Psum[(n0 + tid)*4096 + row] = v;
    }
    // round 2: sumsq
    __syncthreads();
    #pragma unroll
    for (int j = 0; j < 4; ++j) Red[ty][tx*4+j] = pq[j];
    __syncthreads();
    if (tid < 64) {
      float v = 0.f;
      #pragma unroll
      for (int t = 0; t < 16; ++t) v += Red[t][tid];
      Psq[(n0 + tid)*4096 + row] = v;
    }
    // round 3: max over k (rows grouped 16 per s; ty groups of 4 share one s)
    __syncthreads();
    #pragma unroll
    for (int j = 0; j < 4; ++j) Red[ty][tx*4+j] = mx[j];
    __syncthreads();
    {
      const int sl = tid >> 6, ch = tid & 63;
      float v = Red[sl*4+0][ch];
      v = fmaxf(v, Red[sl*4+1][ch]);
      v = fmaxf(v, Red[sl*4+2][ch]);
      v = fmaxf(v, Red[sl*4+3][ch]);
      maxv[((size_t)((b<<10) + by*4 + sl))*C1 + n0 + ch] = v;
    }
    // round 4: min over k
    __syncthreads();
    #pragma unroll
    for (int j = 0; j < 4; ++j) Red[ty][tx*4+j] = mn[j];
    __syncthreads();
    {
      const int sl = tid >> 6, ch = tid & 63;
      float v = Red[sl*4+0][ch];
      v = fminf(v, Red[sl*4+1][ch]);
      v = fminf(v, Red[sl*4+2][ch]);
      v = fminf(v, Red[sl*4+3][ch]);
      minv[((size_t)((b<<10) + by*4 + sl))*C1 + n0 + ch] = v;
    }
  }
}

// ---------------- final: BN2 + relu on max/min ----------------
__global__ __launch_bounds__(256) void final_kernel(
    const float* __restrict__ maxv, const float* __restrict__ minv,
    const float* __restrict__ scale2, const float* __restrict__ shift2,
    float* __restrict__ out)
{
  const int bs = blockIdx.x;      // b*1024 + s
  const int n  = threadIdx.x;
  const float sc = scale2[n], sh = shift2[n];
  const size_t idx = (size_t)bs * C1 + n;
  const float sel = (sc >= 0.0f) ? maxv[idx] : minv[idx];
  out[(size_t)BB*SS*3 + idx] = fmaxf(sc*sel + sh, 0.0f);
}

extern "C" void kernel_launch(void* const* d_in, const int* in_sizes, int n_in,
                              void* d_out, int out_size, void* d_ws, size_t ws_size,
                              hipStream_t stream) {
  const float* xyz    = (const float*)d_in[0];
  const float* points = (const float*)d_in[1];
  const float* W1     = (const float*)d_in[2];
  const float* b1     = (const float*)d_in[3];
  const float* g1     = (const float*)d_in[4];
  const float* bt1    = (const float*)d_in[5];
  const float* W2     = (const float*)d_in[6];
  const float* b2     = (const float*)d_in[7];
  const float* g2     = (const float*)d_in[8];
  const float* bt2    = (const float*)d_in[9];
  float* out = (float*)d_out;
  char* ws = (char*)d_ws;

  // workspace layout (total ~41 MB)
  int*   knn_idx = (int*)(ws + 0);                  //  1,048,576
  float* Ps      = (float*)(ws + 1048576ULL);       //  4,194,304  (shared by BN1 then BN2)
  float* Pq      = (float*)(ws + 5242880ULL);       //  4,194,304
  float* sc1     = (float*)(ws + 9437184ULL);       //  1024
  float* sh1     = (float*)(ws + 9438208ULL);       //  1024
  float* sc2     = (float*)(ws + 9439232ULL);       //  1024
  float* sh2     = (float*)(ws + 9440256ULL);       //  1024
  float* maxv    = (float*)(ws + 9441280ULL);       // 16,777,216
  float* minv    = (float*)(ws + 26218496ULL);      // 16,777,216  -> ends 42,995,712

  float* new_xyz = out; // first 16*1024*3 floats of d_out

  fps_kernel<<<BB, 256, 0, stream>>>(xyz, new_xyz);
  knn_kernel<<<64, 256, 0, stream>>>(xyz, new_xyz, knn_idx);
  gemm1_stats_kernel<<<dim3(4,256,BB), 256, 0, stream>>>(xyz, points, W1, b1, knn_idx, new_xyz, Ps, Pq);
  stats_kernel<<<256, 256, 0, stream>>>(Ps, Pq, g1, bt1, sc1, sh1);
  fused2_kernel<<<dim3(256,BB), 256, 0, stream>>>(xyz, points, W1, b1, knn_idx, new_xyz,
                                                  sc1, sh1, W2, b2, maxv, minv, Ps, Pq);
  stats_kernel<<<256, 256, 0, stream>>>(Ps, Pq, g2, bt2, sc2, sh2);
  final_kernel<<<BB*SS, 256, 0, stream>>>(maxv, minv, sc2, sh2, out);
}

// Round 3
// 2129.885 us; speedup vs baseline: 2.4257x; 2.4257x over previous
//
#include <hip/hip_runtime.h>
#include <hip/hip_bf16.h>
#include <cstdint>
#include <cstddef>

#define BB   16
#define NN   4096
#define DD   128
#define SS   1024
#define CIN  131
#define C1   256
#define MM   (SS*16)

#define FP 168   // Fs pitch (bf16 elems): 336B, 16B-aligned, 2-way banks
#define WP 40    // Ws pitch: 80B
#define AP 264   // As pitch: 528B

typedef __attribute__((ext_vector_type(8))) short bf16x8;
typedef __attribute__((ext_vector_type(4))) float f32x4;

__device__ __forceinline__ float bf2f(unsigned short u) {
  union { unsigned int i; float f; } x; x.i = ((unsigned int)u) << 16; return x.f;
}
__device__ __forceinline__ unsigned short f2bf(float f) {
  union { __hip_bfloat16 h; unsigned short u; } c; c.h = __float2bfloat16(f); return c.u;
}

// ---------------- weight convert: fp32 -> bf16, W1 column-permuted (points first, xyz last, zero pad) ----------------
__global__ __launch_bounds__(256) void convert_kernel(
    const float* __restrict__ W1, const float* __restrict__ W2,
    unsigned short* __restrict__ W1b, unsigned short* __restrict__ W2b)
{
  const int n = blockIdx.x, t = threadIdx.x;
  if (t < 160) {
    float v = 0.0f;
    if (t < 128)      v = W1[n*CIN + 3 + t];
    else if (t < 131) v = W1[n*CIN + (t - 128)];
    W1b[n*160 + t] = f2bf(v);
  }
  W2b[n*256 + t] = f2bf(W2[n*256 + t]);
}

// ---------------- FPS: 1024 threads, DPP wave-argmax, 1 barrier/iter ----------------
__global__ __launch_bounds__(1024) void fps_kernel(
    const float* __restrict__ xyz, float* __restrict__ out_xyz)
{
  __shared__ float xs[NN], ys[NN], zs[NN];
  __shared__ unsigned long long wres[2][16];
  const int b = blockIdx.x;
  const int tid = threadIdx.x;
  const int wave = tid >> 6, lane = tid & 63;
  const float* base = xyz + (size_t)b * NN * 3;
  for (int i = tid; i < NN; i += 1024) {
    xs[i] = base[i*3+0]; ys[i] = base[i*3+1]; zs[i] = base[i*3+2];
  }
  __syncthreads();
  float mind[4];
  #pragma unroll
  for (int j = 0; j < 4; ++j) mind[j] = 1e10f;
  int far = 0;
  for (int it = 0; it < SS; ++it) {
    if (tid == 0) {
      out_xyz[(b*SS + it)*3 + 0] = xs[far];
      out_xyz[(b*SS + it)*3 + 1] = ys[far];
      out_xyz[(b*SS + it)*3 + 2] = zs[far];
    }
    const float cx = xs[far], cy = ys[far], cz = zs[far];
    unsigned long long best = 0;
    #pragma unroll
    for (int j = 0; j < 4; ++j) {
      const int p = j*1024 + tid;
      float dx = __fsub_rn(xs[p], cx);
      float dy = __fsub_rn(ys[p], cy);
      float dz = __fsub_rn(zs[p], cz);
      float d  = __fadd_rn(__fadd_rn(__fmul_rn(dx,dx), __fmul_rn(dy,dy)), __fmul_rn(dz,dz));
      float md = fminf(mind[j], d);
      mind[j] = md;
      unsigned long long key = ((unsigned long long)__float_as_uint(md) << 32)
                             | (unsigned int)(~(unsigned int)p);
      if (key > best) best = key;
    }
    // wave argmax via DPP: row_shr 1,2,4,8 then bcast15, bcast31 -> lane 63
    #define FPS_STEP(CTRL) { \
      unsigned int lo = (unsigned int)best, hi = (unsigned int)(best >> 32); \
      unsigned int lo2 = (unsigned int)__builtin_amdgcn_update_dpp((int)lo, (int)lo, CTRL, 0xf, 0xf, false); \
      unsigned int hi2 = (unsigned int)__builtin_amdgcn_update_dpp((int)hi, (int)hi, CTRL, 0xf, 0xf, false); \
      unsigned long long o = (((unsigned long long)hi2) << 32) | lo2; \
      if (o > best) best = o; }
    FPS_STEP(0x111) FPS_STEP(0x112) FPS_STEP(0x114) FPS_STEP(0x118)
    FPS_STEP(0x142) FPS_STEP(0x143)
    #undef FPS_STEP
    const int par = it & 1;
    if (lane == 63) wres[par][wave] = best;
    __syncthreads();
    unsigned long long g = wres[par][0];
    #pragma unroll
    for (int w = 1; w < 16; ++w) {
      unsigned long long o = wres[par][w];
      if (o > g) g = o;
    }
    far = (int)(~(unsigned int)g);
  }
}

// ---------------- kNN: 64-thread blocks (256 blocks), top-16 insertion sort ----------------
__global__ __launch_bounds__(64) void knn_kernel(
    const float* __restrict__ xyz, const float* __restrict__ new_xyz, int* __restrict__ knn_idx)
{
  __shared__ float tx_[512], ty_[512], tz_[512];
  const int b = blockIdx.y;
  const int s = (blockIdx.x << 6) + threadIdx.x;
  const float cx = new_xyz[((b<<10)+s)*3+0];
  const float cy = new_xyz[((b<<10)+s)*3+1];
  const float cz = new_xyz[((b<<10)+s)*3+2];
  float td[16]; int ti[16];
  #pragma unroll
  for (int j = 0; j < 16; ++j) { td[j] = 3.4e38f; ti[j] = 0; }
  const float* base = xyz + (size_t)b*NN*3;
  for (int t0 = 0; t0 < NN; t0 += 512) {
    __syncthreads();
    for (int i = threadIdx.x; i < 512; i += 64) {
      tx_[i] = base[(t0+i)*3+0]; ty_[i] = base[(t0+i)*3+1]; tz_[i] = base[(t0+i)*3+2];
    }
    __syncthreads();
    for (int i = 0; i < 512; ++i) {
      float dx = __fsub_rn(tx_[i], cx);
      float dy = __fsub_rn(ty_[i], cy);
      float dz = __fsub_rn(tz_[i], cz);
      float d  = __fadd_rn(__fadd_rn(__fmul_rn(dx,dx), __fmul_rn(dy,dy)), __fmul_rn(dz,dz));
      if (d < td[15]) {
        td[15] = d; ti[15] = t0 + i;
        #pragma unroll
        for (int j = 15; j > 0; --j) {
          if (td[j] < td[j-1]) {
            float tf = td[j]; td[j] = td[j-1]; td[j-1] = tf;
            int   tt = ti[j]; ti[j] = ti[j-1]; ti[j-1] = tt;
          }
        }
      }
    }
  }
  int* o = knn_idx + ((size_t)((b<<10)+s))*16;
  #pragma unroll
  for (int j = 0; j < 16; ++j) o[j] = ti[j];
}

// ---- helper: stage gathered feature tile (64 rows x 160 k, bf16, k-contig) into LDS ----
__device__ __forceinline__ void stage_features(
    unsigned short* Fs, const float* xyz, const float* points,
    const int* knn_idx, const float* new_xyz, int b, int by, int tid)
{
  const int rg = tid >> 2, cg = tid & 3;
  const int m = by*64 + rg;
  const int s = m >> 4, kk = m & 15;
  const int p = knn_idx[((b<<10)+s)*16 + kk];
  const float4* pb = (const float4*)(points + ((size_t)b*NN + p) * DD);
  unsigned short* row = Fs + rg*FP;
  #pragma unroll
  for (int i = 0; i < 8; ++i) {
    float4 v = pb[cg*8 + i];
    ushort4 u;
    u.x = f2bf(v.x); u.y = f2bf(v.y); u.z = f2bf(v.z); u.w = f2bf(v.w);
    *(ushort4*)&row[cg*32 + i*4] = u;
  }
  if (cg == 0) {
    float c3[3];
    c3[0] = xyz[((size_t)b*NN + p)*3+0] - new_xyz[((b<<10)+s)*3+0];
    c3[1] = xyz[((size_t)b*NN + p)*3+1] - new_xyz[((b<<10)+s)*3+1];
    c3[2] = xyz[((size_t)b*NN + p)*3+2] - new_xyz[((b<<10)+s)*3+2];
    #pragma unroll
    for (int k = 128; k < 160; k += 4) {
      ushort4 u;
      u.x = f2bf(k+0 < 131 ? c3[k-128+0] : 0.0f);
      u.y = f2bf(k+1 < 131 ? c3[k-128+1] : 0.0f);
      u.z = f2bf(k+2 < 131 ? c3[k-128+2] : 0.0f);
      u.w = f2bf(k+3 < 131 ? c3[k-128+3] : 0.0f);
      *(ushort4*)&row[k] = u;
    }
  }
}

// ---------------- pass A: y1 (MFMA) -> BN1 partials only ----------------
__global__ __launch_bounds__(256, 2) void gemm1_stats_kernel(
    const float* __restrict__ xyz, const float* __restrict__ points,
    const unsigned short* __restrict__ W1b, const float* __restrict__ bias1,
    const int* __restrict__ knn_idx, const float* __restrict__ new_xyz,
    float* __restrict__ Psum, float* __restrict__ Psq)
{
  __shared__ unsigned short Fs[64*FP];    // 21504 B
  __shared__ unsigned short Ws[256*WP];   // 20480 B
  __shared__ float RedS[1024];            // 4096 B
  __shared__ float RedQ[1024];            // 4096 B
  const int by = blockIdx.x, b = blockIdx.y;
  const int tid = threadIdx.x;
  const int wave = tid >> 6, lane = tid & 63;
  const int m15 = lane & 15, quad = lane >> 4;
  const int n0w = wave * 64;

  stage_features(Fs, xyz, points, knn_idx, new_xyz, b, by, tid);

  f32x4 acc[4][4];
  #pragma unroll
  for (int t = 0; t < 4; ++t)
    #pragma unroll
    for (int u = 0; u < 4; ++u) acc[t][u] = (f32x4){0.f,0.f,0.f,0.f};

  for (int kc = 0; kc < 5; ++kc) {
    const int k0 = kc * 32;
    __syncthreads();
    {
      const uint4* src = (const uint4*)(W1b + (size_t)tid*160 + k0);
      uint4* dst = (uint4*)(Ws + tid*WP);
      #pragma unroll
      for (int i = 0; i < 4; ++i) dst[i] = src[i];
    }
    __syncthreads();
    bf16x8 af[4], bfr[4];
    #pragma unroll
    for (int t = 0; t < 4; ++t) af[t]  = *(const bf16x8*)&Fs[(t*16 + m15)*FP + k0 + quad*8];
    #pragma unroll
    for (int u = 0; u < 4; ++u) bfr[u] = *(const bf16x8*)&Ws[(n0w + u*16 + m15)*WP + quad*8];
    #pragma unroll
    for (int t = 0; t < 4; ++t)
      #pragma unroll
      for (int u = 0; u < 4; ++u)
        acc[t][u] = __builtin_amdgcn_mfma_f32_16x16x32_bf16(af[t], bfr[u], acc[t][u], 0, 0, 0);
  }

  // epilogue: per-channel sum / sumsq
  #pragma unroll
  for (int u = 0; u < 4; ++u) {
    const int n = n0w + u*16 + m15;
    const float bias = bias1[n];
    float ps = 0.f, pq = 0.f;
    #pragma unroll
    for (int t = 0; t < 4; ++t)
      #pragma unroll
      for (int r = 0; r < 4; ++r) {
        float y = acc[t][u][r] + bias;
        ps += y; pq += y*y;
      }
    RedS[n*4 + quad] = ps;
    RedQ[n*4 + quad] = pq;
  }
  __syncthreads();
  {
    const int n = tid;
    float4 s4 = *(const float4*)&RedS[n*4];
    float4 q4 = *(const float4*)&RedQ[n*4];
    const int row = b*256 + by;
    Psum[(size_t)n*4096 + row] = (s4.x + s4.y) + (s4.z + s4.w);
    Psq [(size_t)n*4096 + row] = (q4.x + q4.y) + (q4.z + q4.w);
  }
}

// ---------------- stats: per-channel mean/var -> scale/shift ----------------
__global__ __launch_bounds__(256) void stats_kernel(
    const float* __restrict__ Psum, const float* __restrict__ Psq,
    const float* __restrict__ gamma, const float* __restrict__ beta,
    float* __restrict__ scale, float* __restrict__ shift)
{
  __shared__ float sv[4], qv[4];
  const int c = blockIdx.x, tid = threadIdx.x;
  float s = 0.f, q = 0.f;
  for (int r = tid; r < 4096; r += 256) { s += Psum[(size_t)c*4096+r]; q += Psq[(size_t)c*4096+r]; }
  #pragma unroll
  for (int off = 32; off > 0; off >>= 1) { s += __shfl_down(s, off); q += __shfl_down(q, off); }
  if ((tid & 63) == 0) { sv[tid>>6] = s; qv[tid>>6] = q; }
  __syncthreads();
  if (tid == 0) {
    s = sv[0]+sv[1]+sv[2]+sv[3]; q = qv[0]+qv[1]+qv[2]+qv[3];
    const float count = 262144.0f;
    float mean = s / count;
    float var  = fmaxf(q / count - mean*mean, 0.0f);
    float inv  = 1.0f / sqrtf(var + 1e-5f);
    float sc   = gamma[c] * inv;
    scale[c] = sc;
    shift[c] = beta[c] - mean * sc;
  }
}

// ---------------- fused: y1 (MFMA) -> bn1+relu -> y2 (MFMA) -> BN2 partials + max/min over K ----------------
__global__ __launch_bounds__(256, 2) void fused2_kernel(
    const float* __restrict__ xyz, const float* __restrict__ points,
    const unsigned short* __restrict__ W1b, const float* __restrict__ bias1,
    const int* __restrict__ knn_idx, const float* __restrict__ new_xyz,
    const float* __restrict__ sc1v, const float* __restrict__ sh1v,
    const unsigned short* __restrict__ W2b, const float* __restrict__ bias2,
    float* __restrict__ maxv, float* __restrict__ minv,
    float* __restrict__ Psum, float* __restrict__ Psq)
{
  __shared__ char smem[58368];
  unsigned short* As_  = (unsigned short*)smem;            // 64*264*2 = 33792 (aliases Fs)
  unsigned short* Fs   = (unsigned short*)smem;            // 64*168*2 = 21504
  unsigned short* Ws   = (unsigned short*)(smem + 33792);  // 256*40*2 = 20480
  float* RedS  = (float*)(smem + 33792);                   // 4096 (aliases Ws, after barrier)
  float* RedQ  = (float*)(smem + 37888);                   // 4096
  float* MMBuf = (float*)(smem + 41984);                   // 4*256*4*4 = 16384

  const int by = blockIdx.x, b = blockIdx.y;
  const int tid = threadIdx.x;
  const int wave = tid >> 6, lane = tid & 63;
  const int m15 = lane & 15, quad = lane >> 4;
  const int n0w = wave * 64;

  stage_features(Fs, xyz, points, knn_idx, new_xyz, b, by, tid);

  f32x4 acc[4][4];
  #pragma unroll
  for (int t = 0; t < 4; ++t)
    #pragma unroll
    for (int u = 0; u < 4; ++u) acc[t][u] = (f32x4){0.f,0.f,0.f,0.f};

  // ---- stage 1: y1 = F @ W1^T ----
  for (int kc = 0; kc < 5; ++kc) {
    const int k0 = kc * 32;
    __syncthreads();
    {
      const uint4* src = (const uint4*)(W1b + (size_t)tid*160 + k0);
      uint4* dst = (uint4*)(Ws + tid*WP);
      #pragma unroll
      for (int i = 0; i < 4; ++i) dst[i] = src[i];
    }
    __syncthreads();
    bf16x8 af[4], bfr[4];
    #pragma unroll
    for (int t = 0; t < 4; ++t) af[t]  = *(const bf16x8*)&Fs[(t*16 + m15)*FP + k0 + quad*8];
    #pragma unroll
    for (int u = 0; u < 4; ++u) bfr[u] = *(const bf16x8*)&Ws[(n0w + u*16 + m15)*WP + quad*8];
    #pragma unroll
    for (int t = 0; t < 4; ++t)
      #pragma unroll
      for (int u = 0; u < 4; ++u)
        acc[t][u] = __builtin_amdgcn_mfma_f32_16x16x32_bf16(af[t], bfr[u], acc[t][u], 0, 0, 0);
  }

  __syncthreads();  // all Fs reads done before As overwrites it

  // bn1 + relu -> As (bf16, [m][n] with n as k-dim for stage 2)
  #pragma unroll
  for (int u = 0; u < 4; ++u) {
    const int n = n0w + u*16 + m15;
    const float bias = bias1[n], sc = sc1v[n], sh = sh1v[n];
    #pragma unroll
    for (int t = 0; t < 4; ++t)
      #pragma unroll
      for (int r = 0; r < 4; ++r) {
        float a = fmaxf((acc[t][u][r] + bias)*sc + sh, 0.0f);
        As_[(t*16 + quad*4 + r)*AP + n] = f2bf(a);
      }
  }

  #pragma unroll
  for (int t = 0; t < 4; ++t)
    #pragma unroll
    for (int u = 0; u < 4; ++u) acc[t][u] = (f32x4){0.f,0.f,0.f,0.f};

  // ---- stage 2: y2 = A @ W2^T ----
  for (int kc = 0; kc < 8; ++kc) {
    const int k0 = kc * 32;
    __syncthreads();
    {
      const uint4* src = (const uint4*)(W2b + (size_t)tid*256 + k0);
      uint4* dst = (uint4*)(Ws + tid*WP);
      #pragma unroll
      for (int i = 0; i < 4; ++i) dst[i] = src[i];
    }
    __syncthreads();
    bf16x8 af[4], bfr[4];
    #pragma unroll
    for (int t = 0; t < 4; ++t) af[t]  = *(const bf16x8*)&As_[(t*16 + m15)*AP + k0 + quad*8];
    #pragma unroll
    for (int u = 0; u < 4; ++u) bfr[u] = *(const bf16x8*)&Ws[(n0w + u*16 + m15)*WP + quad*8];
    #pragma unroll
    for (int t = 0; t < 4; ++t)
      #pragma unroll
      for (int u = 0; u < 4; ++u)
        acc[t][u] = __builtin_amdgcn_mfma_f32_16x16x32_bf16(af[t], bfr[u], acc[t][u], 0, 0, 0);
  }

  __syncthreads();  // Ws reads done; Red/MMBuf alias it

  // epilogue: per-channel sum/sq + per-(s,n) max over the 16-row group
  float mxv[4][4], mnv[4][4];
  #pragma unroll
  for (int u = 0; u < 4; ++u) {
    const int n = n0w + u*16 + m15;
    const float bias = bias2[n];
    float ps = 0.f, pq = 0.f;
    #pragma unroll
    for (int t = 0; t < 4; ++t) {
      float y0 = acc[t][u][0] + bias, y1 = acc[t][u][1] + bias;
      float y2 = acc[t][u][2] + bias, y3 = acc[t][u][3] + bias;
      ps += ((y0 + y1) + (y2 + y3));
      pq += ((y0*y0 + y1*y1) + (y2*y2 + y3*y3));
      mxv[t][u] = fmaxf(fmaxf(y0, y1), fmaxf(y2, y3));
      mnv[t][u] = fminf(fminf(y0, y1), fminf(y2, y3));
    }
    RedS[n*4 + quad] = ps;
    RedQ[n*4 + quad] = pq;
    #pragma unroll
    for (int t = 0; t < 4; ++t) MMBuf[(t*256 + n)*4 + quad] = mxv[t][u];
  }
  __syncthreads();
  {
    const int n = tid;
    float4 s4 = *(const float4*)&RedS[n*4];
    float4 q4 = *(const float4*)&RedQ[n*4];
    const int row = b*256 + by;
    Psum[(size_t)n*4096 + row] = (s4.x + s4.y) + (s4.z + s4.w);
    Psq [(size_t)n*4096 + row] = (q4.x + q4.y) + (q4.z + q4.w);
    #pragma unroll
    for (int j = 0; j < 4; ++j) {
      float4 m4 = *(const float4*)&MMBuf[(j*256 + n)*4];
      float v = fmaxf(fmaxf(m4.x, m4.y), fmaxf(m4.z, m4.w));
      maxv[((size_t)((b<<10) + by*4 + j))*C1 + n] = v;
    }
  }
  __syncthreads();
  #pragma unroll
  for (int u = 0; u < 4; ++u) {
    const int n = n0w + u*16 + m15;
    #pragma unroll
    for (int t = 0; t < 4; ++t) MMBuf[(t*256 + n)*4 + quad] = mnv[t][u];
  }
  __syncthreads();
  {
    const int n = tid;
    #pragma unroll
    for (int j = 0; j < 4; ++j) {
      float4 m4 = *(const float4*)&MMBuf[(j*256 + n)*4];
      float v = fminf(fminf(m4.x, m4.y), fminf(m4.z, m4.w));
      minv[((size_t)((b<<10) + by*4 + j))*C1 + n] = v;
    }
  }
}

// ---------------- final: BN2 + relu on max/min ----------------
__global__ __launch_bounds__(256) void final_kernel(
    const float* __restrict__ maxv, const float* __restrict__ minv,
    const float* __restrict__ scale2, const float* __restrict__ shift2,
    float* __restrict__ out)
{
  const int bs = blockIdx.x;
  const int n  = threadIdx.x;
  const float sc = scale2[n], sh = shift2[n];
  const size_t idx = (size_t)bs * C1 + n;
  const float sel = (sc >= 0.0f) ? maxv[idx] : minv[idx];
  out[(size_t)BB*SS*3 + idx] = fmaxf(sc*sel + sh, 0.0f);
}

extern "C" void kernel_launch(void* const* d_in, const int* in_sizes, int n_in,
                              void* d_out, int out_size, void* d_ws, size_t ws_size,
                              hipStream_t stream) {
  const float* xyz    = (const float*)d_in[0];
  const float* points = (const float*)d_in[1];
  const float* W1     = (const float*)d_in[2];
  const float* b1     = (const float*)d_in[3];
  const float* g1     = (const float*)d_in[4];
  const float* bt1    = (const float*)d_in[5];
  const float* W2     = (const float*)d_in[6];
  const float* b2     = (const float*)d_in[7];
  const float* g2     = (const float*)d_in[8];
  const float* bt2    = (const float*)d_in[9];
  float* out = (float*)d_out;
  char* ws = (char*)d_ws;

  int*   knn_idx = (int*)(ws + 0);                    //  1,048,576
  float* Ps      = (float*)(ws + 1048576ULL);         //  4,194,304
  float* Pq      = (float*)(ws + 5242880ULL);         //  4,194,304
  float* sc1     = (float*)(ws + 9437184ULL);
  float* sh1     = (float*)(ws + 9438208ULL);
  float* sc2     = (float*)(ws + 9439232ULL);
  float* sh2     = (float*)(ws + 9440256ULL);
  float* maxv    = (float*)(ws + 9441280ULL);         // 16,777,216
  float* minv    = (float*)(ws + 26218496ULL);        // 16,777,216
  unsigned short* W1b = (unsigned short*)(ws + 42995712ULL);  // 81,920
  unsigned short* W2b = (unsigned short*)(ws + 43077632ULL);  // 131,072 -> ends 43,208,704

  float* new_xyz = out;

  convert_kernel<<<256, 256, 0, stream>>>(W1, W2, W1b, W2b);
  fps_kernel<<<BB, 1024, 0, stream>>>(xyz, new_xyz);
  knn_kernel<<<dim3(16, BB), 64, 0, stream>>>(xyz, new_xyz, knn_idx);
  gemm1_stats_kernel<<<dim3(256, BB), 256, 0, stream>>>(xyz, points, W1b, b1, knn_idx, new_xyz, Ps, Pq);
  stats_kernel<<<256, 256, 0, stream>>>(Ps, Pq, g1, bt1, sc1, sh1);
  fused2_kernel<<<dim3(256, BB), 256, 0, stream>>>(xyz, points, W1b, b1, knn_idx, new_xyz,
                                                   sc1, sh1, W2b, b2, maxv, minv, Ps, Pq);
  stats_kernel<<<256, 256, 0, stream>>>(Ps, Pq, g2, bt2, sc2, sh2);
  final_kernel<<<BB*SS, 256, 0, stream>>>(maxv, minv, sc2, sh2, out);
}

// Round 4
// 1776.129 us; speedup vs baseline: 2.9088x; 1.1992x over previous
//
#include <hip/hip_runtime.h>
#include <hip/hip_bf16.h>
#include <cstdint>
#include <cstddef>

#define BB   16
#define NN   4096
#define DD   128
#define SS   1024
#define CIN  131
#define C1   256
#define MM   (SS*16)

#define FP 168   // Fs pitch (bf16 elems)
#define WP 40    // Ws pitch
#define AP 264   // As pitch

typedef __attribute__((ext_vector_type(8))) short bf16x8;
typedef __attribute__((ext_vector_type(4))) float f32x4;

__device__ __forceinline__ float bf2f(unsigned short u) {
  union { unsigned int i; float f; } x; x.i = ((unsigned int)u) << 16; return x.f;
}
__device__ __forceinline__ unsigned short f2bf(float f) {
  union { __hip_bfloat16 h; unsigned short u; } c; c.h = __float2bfloat16(f); return c.u;
}

// ---------------- weight convert ----------------
__global__ __launch_bounds__(256) void convert_kernel(
    const float* __restrict__ W1, const float* __restrict__ W2,
    unsigned short* __restrict__ W1b, unsigned short* __restrict__ W2b)
{
  const int n = blockIdx.x, t = threadIdx.x;
  if (t < 160) {
    float v = 0.0f;
    if (t < 128)      v = W1[n*CIN + 3 + t];
    else if (t < 131) v = W1[n*CIN + (t - 128)];
    W1b[n*160 + t] = f2bf(v);
  }
  W2b[n*256 + t] = f2bf(W2[n*256 + t]);
}

// ---------------- FPS v3: 256 threads, 16 pts/thread in REGISTERS, DPP wave-argmax ----------------
__global__ __launch_bounds__(256) void fps_kernel(
    const float* __restrict__ xyz, float* __restrict__ out_xyz)
{
  __shared__ float xs[NN], ys[NN], zs[NN];
  __shared__ unsigned long long wres[2][4];
  const int b = blockIdx.x;
  const int tid = threadIdx.x;
  const int wave = tid >> 6, lane = tid & 63;
  const float* base = xyz + (size_t)b * NN * 3;
  for (int i = tid; i < NN; i += 256) {
    xs[i] = base[i*3+0]; ys[i] = base[i*3+1]; zs[i] = base[i*3+2];
  }
  __syncthreads();
  float px[16], py[16], pz[16], mind[16];
  #pragma unroll
  for (int j = 0; j < 16; ++j) {
    px[j] = xs[j*256 + tid];
    py[j] = ys[j*256 + tid];
    pz[j] = zs[j*256 + tid];
    mind[j] = 1e10f;
  }
  int far = 0;
  for (int it = 0; it < SS; ++it) {
    if (tid == 0) {
      out_xyz[(b*SS + it)*3 + 0] = xs[far];
      out_xyz[(b*SS + it)*3 + 1] = ys[far];
      out_xyz[(b*SS + it)*3 + 2] = zs[far];
    }
    const float cx = xs[far], cy = ys[far], cz = zs[far];
    float bv = -1.0f; int bj = 0;
    #pragma unroll
    for (int j = 0; j < 16; ++j) {
      float dx = __fsub_rn(px[j], cx);
      float dy = __fsub_rn(py[j], cy);
      float dz = __fsub_rn(pz[j], cz);
      float d  = __fadd_rn(__fadd_rn(__fmul_rn(dx,dx), __fmul_rn(dy,dy)), __fmul_rn(dz,dz));
      float md = fminf(mind[j], d);
      mind[j] = md;
      if (md > bv) { bv = md; bj = j; }   // strict >: earliest j wins -> smallest p
    }
    unsigned long long best = ((unsigned long long)__float_as_uint(bv) << 32)
                            | (unsigned int)(~(unsigned int)(bj*256 + tid));
    // wave argmax via DPP: row_shr 1,2,4,8 then bcast15, bcast31 -> lane 63 has wave max
    #define FPS_STEP(CTRL) { \
      unsigned int lo = (unsigned int)best, hi = (unsigned int)(best >> 32); \
      unsigned int lo2 = (unsigned int)__builtin_amdgcn_update_dpp((int)lo, (int)lo, CTRL, 0xf, 0xf, false); \
      unsigned int hi2 = (unsigned int)__builtin_amdgcn_update_dpp((int)hi, (int)hi, CTRL, 0xf, 0xf, false); \
      unsigned long long o = (((unsigned long long)hi2) << 32) | lo2; \
      if (o > best) best = o; }
    FPS_STEP(0x111) FPS_STEP(0x112) FPS_STEP(0x114) FPS_STEP(0x118)
    FPS_STEP(0x142) FPS_STEP(0x143)
    #undef FPS_STEP
    const int par = it & 1;
    if (lane == 63) wres[par][wave] = best;
    __syncthreads();
    unsigned long long g = wres[par][0];
    #pragma unroll
    for (int w = 1; w < 4; ++w) {
      unsigned long long o = wres[par][w];
      if (o > g) g = o;
    }
    far = (int)(~(unsigned int)g);
  }
}

// ---------------- kNN: 64-thread blocks (256 blocks), top-16 insertion sort ----------------
__global__ __launch_bounds__(64) void knn_kernel(
    const float* __restrict__ xyz, const float* __restrict__ new_xyz, int* __restrict__ knn_idx)
{
  __shared__ float tx_[512], ty_[512], tz_[512];
  const int b = blockIdx.y;
  const int s = (blockIdx.x << 6) + threadIdx.x;
  const float cx = new_xyz[((b<<10)+s)*3+0];
  const float cy = new_xyz[((b<<10)+s)*3+1];
  const float cz = new_xyz[((b<<10)+s)*3+2];
  float td[16]; int ti[16];
  #pragma unroll
  for (int j = 0; j < 16; ++j) { td[j] = 3.4e38f; ti[j] = 0; }
  const float* base = xyz + (size_t)b*NN*3;
  for (int t0 = 0; t0 < NN; t0 += 512) {
    __syncthreads();
    for (int i = threadIdx.x; i < 512; i += 64) {
      tx_[i] = base[(t0+i)*3+0]; ty_[i] = base[(t0+i)*3+1]; tz_[i] = base[(t0+i)*3+2];
    }
    __syncthreads();
    for (int i = 0; i < 512; ++i) {
      float dx = __fsub_rn(tx_[i], cx);
      float dy = __fsub_rn(ty_[i], cy);
      float dz = __fsub_rn(tz_[i], cz);
      float d  = __fadd_rn(__fadd_rn(__fmul_rn(dx,dx), __fmul_rn(dy,dy)), __fmul_rn(dz,dz));
      if (d < td[15]) {
        td[15] = d; ti[15] = t0 + i;
        #pragma unroll
        for (int j = 15; j > 0; --j) {
          if (td[j] < td[j-1]) {
            float tf = td[j]; td[j] = td[j-1]; td[j-1] = tf;
            int   tt = ti[j]; ti[j] = ti[j-1]; ti[j-1] = tt;
          }
        }
      }
    }
  }
  int* o = knn_idx + ((size_t)((b<<10)+s))*16;
  #pragma unroll
  for (int j = 0; j < 16; ++j) o[j] = ti[j];
}

// ---- helper: stage gathered feature tile into LDS ----
__device__ __forceinline__ void stage_features(
    unsigned short* Fs, const float* xyz, const float* points,
    const int* knn_idx, const float* new_xyz, int b, int by, int tid)
{
  const int rg = tid >> 2, cg = tid & 3;
  const int m = by*64 + rg;
  const int s = m >> 4, kk = m & 15;
  const int p = knn_idx[((b<<10)+s)*16 + kk];
  const float4* pb = (const float4*)(points + ((size_t)b*NN + p) * DD);
  unsigned short* row = Fs + rg*FP;
  #pragma unroll
  for (int i = 0; i < 8; ++i) {
    float4 v = pb[cg*8 + i];
    ushort4 u;
    u.x = f2bf(v.x); u.y = f2bf(v.y); u.z = f2bf(v.z); u.w = f2bf(v.w);
    *(ushort4*)&row[cg*32 + i*4] = u;
  }
  if (cg == 0) {
    float c3[3];
    c3[0] = xyz[((size_t)b*NN + p)*3+0] - new_xyz[((b<<10)+s)*3+0];
    c3[1] = xyz[((size_t)b*NN + p)*3+1] - new_xyz[((b<<10)+s)*3+1];
    c3[2] = xyz[((size_t)b*NN + p)*3+2] - new_xyz[((b<<10)+s)*3+2];
    #pragma unroll
    for (int k = 128; k < 160; k += 4) {
      ushort4 u;
      u.x = f2bf(k+0 < 131 ? c3[k-128+0] : 0.0f);
      u.y = f2bf(k+1 < 131 ? c3[k-128+1] : 0.0f);
      u.z = f2bf(k+2 < 131 ? c3[k-128+2] : 0.0f);
      u.w = f2bf(k+3 < 131 ? c3[k-128+3] : 0.0f);
      *(ushort4*)&row[k] = u;
    }
  }
}

// ---------------- pass A: y1 (MFMA) -> BN1 partials only ----------------
__global__ __launch_bounds__(256, 2) void gemm1_stats_kernel(
    const float* __restrict__ xyz, const float* __restrict__ points,
    const unsigned short* __restrict__ W1b, const float* __restrict__ bias1,
    const int* __restrict__ knn_idx, const float* __restrict__ new_xyz,
    float* __restrict__ Psum, float* __restrict__ Psq)
{
  __shared__ unsigned short Fs[64*FP];
  __shared__ unsigned short Ws[256*WP];
  __shared__ float RedS[1024];
  __shared__ float RedQ[1024];
  const int by = blockIdx.x, b = blockIdx.y;
  const int tid = threadIdx.x;
  const int wave = tid >> 6, lane = tid & 63;
  const int m15 = lane & 15, quad = lane >> 4;
  const int n0w = wave * 64;

  stage_features(Fs, xyz, points, knn_idx, new_xyz, b, by, tid);

  f32x4 acc[4][4];
  #pragma unroll
  for (int t = 0; t < 4; ++t)
    #pragma unroll
    for (int u = 0; u < 4; ++u) acc[t][u] = (f32x4){0.f,0.f,0.f,0.f};

  for (int kc = 0; kc < 5; ++kc) {
    const int k0 = kc * 32;
    __syncthreads();
    {
      const uint4* src = (const uint4*)(W1b + (size_t)tid*160 + k0);
      uint4* dst = (uint4*)(Ws + tid*WP);
      #pragma unroll
      for (int i = 0; i < 4; ++i) dst[i] = src[i];
    }
    __syncthreads();
    bf16x8 af[4], bfr[4];
    #pragma unroll
    for (int t = 0; t < 4; ++t) af[t]  = *(const bf16x8*)&Fs[(t*16 + m15)*FP + k0 + quad*8];
    #pragma unroll
    for (int u = 0; u < 4; ++u) bfr[u] = *(const bf16x8*)&Ws[(n0w + u*16 + m15)*WP + quad*8];
    #pragma unroll
    for (int t = 0; t < 4; ++t)
      #pragma unroll
      for (int u = 0; u < 4; ++u)
        acc[t][u] = __builtin_amdgcn_mfma_f32_16x16x32_bf16(af[t], bfr[u], acc[t][u], 0, 0, 0);
  }

  #pragma unroll
  for (int u = 0; u < 4; ++u) {
    const int n = n0w + u*16 + m15;
    const float bias = bias1[n];
    float ps = 0.f, pq = 0.f;
    #pragma unroll
    for (int t = 0; t < 4; ++t)
      #pragma unroll
      for (int r = 0; r < 4; ++r) {
        float y = acc[t][u][r] + bias;
        ps += y; pq += y*y;
      }
    RedS[n*4 + quad] = ps;
    RedQ[n*4 + quad] = pq;
  }
  __syncthreads();
  {
    const int n = tid;
    float4 s4 = *(const float4*)&RedS[n*4];
    float4 q4 = *(const float4*)&RedQ[n*4];
    const int row = b*256 + by;
    Psum[(size_t)n*4096 + row] = (s4.x + s4.y) + (s4.z + s4.w);
    Psq [(size_t)n*4096 + row] = (q4.x + q4.y) + (q4.z + q4.w);
  }
}

// ---------------- stats ----------------
__global__ __launch_bounds__(256) void stats_kernel(
    const float* __restrict__ Psum, const float* __restrict__ Psq,
    const float* __restrict__ gamma, const float* __restrict__ beta,
    float* __restrict__ scale, float* __restrict__ shift)
{
  __shared__ float sv[4], qv[4];
  const int c = blockIdx.x, tid = threadIdx.x;
  float s = 0.f, q = 0.f;
  for (int r = tid; r < 4096; r += 256) { s += Psum[(size_t)c*4096+r]; q += Psq[(size_t)c*4096+r]; }
  #pragma unroll
  for (int off = 32; off > 0; off >>= 1) { s += __shfl_down(s, off); q += __shfl_down(q, off); }
  if ((tid & 63) == 0) { sv[tid>>6] = s; qv[tid>>6] = q; }
  __syncthreads();
  if (tid == 0) {
    s = sv[0]+sv[1]+sv[2]+sv[3]; q = qv[0]+qv[1]+qv[2]+qv[3];
    const float count = 262144.0f;
    float mean = s / count;
    float var  = fmaxf(q / count - mean*mean, 0.0f);
    float inv  = 1.0f / sqrtf(var + 1e-5f);
    float sc   = gamma[c] * inv;
    scale[c] = sc;
    shift[c] = beta[c] - mean * sc;
  }
}

// ---------------- fused: y1 (MFMA) -> bn1+relu -> y2 (MFMA) -> BN2 partials + max/min ----------------
__global__ __launch_bounds__(256, 2) void fused2_kernel(
    const float* __restrict__ xyz, const float* __restrict__ points,
    const unsigned short* __restrict__ W1b, const float* __restrict__ bias1,
    const int* __restrict__ knn_idx, const float* __restrict__ new_xyz,
    const float* __restrict__ sc1v, const float* __restrict__ sh1v,
    const unsigned short* __restrict__ W2b, const float* __restrict__ bias2,
    float* __restrict__ maxv, float* __restrict__ minv,
    float* __restrict__ Psum, float* __restrict__ Psq)
{
  __shared__ char smem[58368];
  unsigned short* As_  = (unsigned short*)smem;
  unsigned short* Fs   = (unsigned short*)smem;
  unsigned short* Ws   = (unsigned short*)(smem + 33792);
  float* RedS  = (float*)(smem + 33792);
  float* RedQ  = (float*)(smem + 37888);
  float* MMBuf = (float*)(smem + 41984);

  const int by = blockIdx.x, b = blockIdx.y;
  const int tid = threadIdx.x;
  const int wave = tid >> 6, lane = tid & 63;
  const int m15 = lane & 15, quad = lane >> 4;
  const int n0w = wave * 64;

  stage_features(Fs, xyz, points, knn_idx, new_xyz, b, by, tid);

  f32x4 acc[4][4];
  #pragma unroll
  for (int t = 0; t < 4; ++t)
    #pragma unroll
    for (int u = 0; u < 4; ++u) acc[t][u] = (f32x4){0.f,0.f,0.f,0.f};

  for (int kc = 0; kc < 5; ++kc) {
    const int k0 = kc * 32;
    __syncthreads();
    {
      const uint4* src = (const uint4*)(W1b + (size_t)tid*160 + k0);
      uint4* dst = (uint4*)(Ws + tid*WP);
      #pragma unroll
      for (int i = 0; i < 4; ++i) dst[i] = src[i];
    }
    __syncthreads();
    bf16x8 af[4], bfr[4];
    #pragma unroll
    for (int t = 0; t < 4; ++t) af[t]  = *(const bf16x8*)&Fs[(t*16 + m15)*FP + k0 + quad*8];
    #pragma unroll
    for (int u = 0; u < 4; ++u) bfr[u] = *(const bf16x8*)&Ws[(n0w + u*16 + m15)*WP + quad*8];
    #pragma unroll
    for (int t = 0; t < 4; ++t)
      #pragma unroll
      for (int u = 0; u < 4; ++u)
        acc[t][u] = __builtin_amdgcn_mfma_f32_16x16x32_bf16(af[t], bfr[u], acc[t][u], 0, 0, 0);
  }

  __syncthreads();

  #pragma unroll
  for (int u = 0; u < 4; ++u) {
    const int n = n0w + u*16 + m15;
    const float bias = bias1[n], sc = sc1v[n], sh = sh1v[n];
    #pragma unroll
    for (int t = 0; t < 4; ++t)
      #pragma unroll
      for (int r = 0; r < 4; ++r) {
        float a = fmaxf((acc[t][u][r] + bias)*sc + sh, 0.0f);
        As_[(t*16 + quad*4 + r)*AP + n] = f2bf(a);
      }
  }

  #pragma unroll
  for (int t = 0; t < 4; ++t)
    #pragma unroll
    for (int u = 0; u < 4; ++u) acc[t][u] = (f32x4){0.f,0.f,0.f,0.f};

  for (int kc = 0; kc < 8; ++kc) {
    const int k0 = kc * 32;
    __syncthreads();
    {
      const uint4* src = (const uint4*)(W2b + (size_t)tid*256 + k0);
      uint4* dst = (uint4*)(Ws + tid*WP);
      #pragma unroll
      for (int i = 0; i < 4; ++i) dst[i] = src[i];
    }
    __syncthreads();
    bf16x8 af[4], bfr[4];
    #pragma unroll
    for (int t = 0; t < 4; ++t) af[t]  = *(const bf16x8*)&As_[(t*16 + m15)*AP + k0 + quad*8];
    #pragma unroll
    for (int u = 0; u < 4; ++u) bfr[u] = *(const bf16x8*)&Ws[(n0w + u*16 + m15)*WP + quad*8];
    #pragma unroll
    for (int t = 0; t < 4; ++t)
      #pragma unroll
      for (int u = 0; u < 4; ++u)
        acc[t][u] = __builtin_amdgcn_mfma_f32_16x16x32_bf16(af[t], bfr[u], acc[t][u], 0, 0, 0);
  }

  __syncthreads();

  float mxv[4][4], mnv[4][4];
  #pragma unroll
  for (int u = 0; u < 4; ++u) {
    const int n = n0w + u*16 + m15;
    const float bias = bias2[n];
    float ps = 0.f, pq = 0.f;
    #pragma unroll
    for (int t = 0; t < 4; ++t) {
      float y0 = acc[t][u][0] + bias, y1 = acc[t][u][1] + bias;
      float y2 = acc[t][u][2] + bias, y3 = acc[t][u][3] + bias;
      ps += ((y0 + y1) + (y2 + y3));
      pq += ((y0*y0 + y1*y1) + (y2*y2 + y3*y3));
      mxv[t][u] = fmaxf(fmaxf(y0, y1), fmaxf(y2, y3));
      mnv[t][u] = fminf(fminf(y0, y1), fminf(y2, y3));
    }
    RedS[n*4 + quad] = ps;
    RedQ[n*4 + quad] = pq;
    #pragma unroll
    for (int t = 0; t < 4; ++t) MMBuf[(t*256 + n)*4 + quad] = mxv[t][u];
  }
  __syncthreads();
  {
    const int n = tid;
    float4 s4 = *(const float4*)&RedS[n*4];
    float4 q4 = *(const float4*)&RedQ[n*4];
    const int row = b*256 + by;
    Psum[(size_t)n*4096 + row] = (s4.x + s4.y) + (s4.z + s4.w);
    Psq [(size_t)n*4096 + row] = (q4.x + q4.y) + (q4.z + q4.w);
    #pragma unroll
    for (int j = 0; j < 4; ++j) {
      float4 m4 = *(const float4*)&MMBuf[(j*256 + n)*4];
      float v = fmaxf(fmaxf(m4.x, m4.y), fmaxf(m4.z, m4.w));
      maxv[((size_t)((b<<10) + by*4 + j))*C1 + n] = v;
    }
  }
  __syncthreads();
  #pragma unroll
  for (int u = 0; u < 4; ++u) {
    const int n = n0w + u*16 + m15;
    #pragma unroll
    for (int t = 0; t < 4; ++t) MMBuf[(t*256 + n)*4 + quad] = mnv[t][u];
  }
  __syncthreads();
  {
    const int n = tid;
    #pragma unroll
    for (int j = 0; j < 4; ++j) {
      float4 m4 = *(const float4*)&MMBuf[(j*256 + n)*4];
      float v = fminf(fminf(m4.x, m4.y), fminf(m4.z, m4.w));
      minv[((size_t)((b<<10) + by*4 + j))*C1 + n] = v;
    }
  }
}

// ---------------- final ----------------
__global__ __launch_bounds__(256) void final_kernel(
    const float* __restrict__ maxv, const float* __restrict__ minv,
    const float* __restrict__ scale2, const float* __restrict__ shift2,
    float* __restrict__ out)
{
  const int bs = blockIdx.x;
  const int n  = threadIdx.x;
  const float sc = scale2[n], sh = shift2[n];
  const size_t idx = (size_t)bs * C1 + n;
  const float sel = (sc >= 0.0f) ? maxv[idx] : minv[idx];
  out[(size_t)BB*SS*3 + idx] = fmaxf(sc*sel + sh, 0.0f);
}

extern "C" void kernel_launch(void* const* d_in, const int* in_sizes, int n_in,
                              void* d_out, int out_size, void* d_ws, size_t ws_size,
                              hipStream_t stream) {
  const float* xyz    = (const float*)d_in[0];
  const float* points = (const float*)d_in[1];
  const float* W1     = (const float*)d_in[2];
  const float* b1     = (const float*)d_in[3];
  const float* g1     = (const float*)d_in[4];
  const float* bt1    = (const float*)d_in[5];
  const float* W2     = (const float*)d_in[6];
  const float* b2     = (const float*)d_in[7];
  const float* g2     = (const float*)d_in[8];
  const float* bt2    = (const float*)d_in[9];
  float* out = (float*)d_out;
  char* ws = (char*)d_ws;

  int*   knn_idx = (int*)(ws + 0);
  float* Ps      = (float*)(ws + 1048576ULL);
  float* Pq      = (float*)(ws + 5242880ULL);
  float* sc1     = (float*)(ws + 9437184ULL);
  float* sh1     = (float*)(ws + 9438208ULL);
  float* sc2     = (float*)(ws + 9439232ULL);
  float* sh2     = (float*)(ws + 9440256ULL);
  float* maxv    = (float*)(ws + 9441280ULL);
  float* minv    = (float*)(ws + 26218496ULL);
  unsigned short* W1b = (unsigned short*)(ws + 42995712ULL);
  unsigned short* W2b = (unsigned short*)(ws + 43077632ULL);

  float* new_xyz = out;

  convert_kernel<<<256, 256, 0, stream>>>(W1, W2, W1b, W2b);
  fps_kernel<<<BB, 256, 0, stream>>>(xyz, new_xyz);
  knn_kernel<<<dim3(16, BB), 64, 0, stream>>>(xyz, new_xyz, knn_idx);
  gemm1_stats_kernel<<<dim3(256, BB), 256, 0, stream>>>(xyz, points, W1b, b1, knn_idx, new_xyz, Ps, Pq);
  stats_kernel<<<256, 256, 0, stream>>>(Ps, Pq, g1, bt1, sc1, sh1);
  fused2_kernel<<<dim3(256, BB), 256, 0, stream>>>(xyz, points, W1b, b1, knn_idx, new_xyz,
                                                   sc1, sh1, W2b, b2, maxv, minv, Ps, Pq);
  stats_kernel<<<256, 256, 0, stream>>>(Ps, Pq, g2, bt2, sc2, sh2);
  final_kernel<<<BB*SS, 256, 0, stream>>>(maxv, minv, sc2, sh2, out);
}

// Round 5
// 1496.959 us; speedup vs baseline: 3.4513x; 1.1865x over previous
//
#include <hip/hip_runtime.h>
#include <hip/hip_bf16.h>
#include <cstdint>
#include <cstddef>

#define BB   16
#define NN   4096
#define DD   128
#define SS   1024
#define CIN  131
#define C1   256
#define MM   (SS*16)

#define FP 168   // Fs pitch (bf16 elems)
#define WP 40    // Ws pitch
#define AP 264   // As pitch

typedef __attribute__((ext_vector_type(8))) short bf16x8;
typedef __attribute__((ext_vector_type(4))) float f32x4;

__device__ __forceinline__ float bf2f(unsigned short u) {
  union { unsigned int i; float f; } x; x.i = ((unsigned int)u) << 16; return x.f;
}
__device__ __forceinline__ unsigned short f2bf(float f) {
  union { __hip_bfloat16 h; unsigned short u; } c; c.h = __float2bfloat16(f); return c.u;
}

// ---------------- weight convert ----------------
__global__ __launch_bounds__(256) void convert_kernel(
    const float* __restrict__ W1, const float* __restrict__ W2,
    unsigned short* __restrict__ W1b, unsigned short* __restrict__ W2b)
{
  const int n = blockIdx.x, t = threadIdx.x;
  if (t < 160) {
    float v = 0.0f;
    if (t < 128)      v = W1[n*CIN + 3 + t];
    else if (t < 131) v = W1[n*CIN + (t - 128)];
    W1b[n*160 + t] = f2bf(v);
  }
  W2b[n*256 + t] = f2bf(W2[n*256 + t]);
}

// ---------------- FPS: 256 threads, 16 pts/thread in registers, DPP wave-argmax ----------------
__global__ __launch_bounds__(256) void fps_kernel(
    const float* __restrict__ xyz, float* __restrict__ out_xyz)
{
  __shared__ float xs[NN], ys[NN], zs[NN];
  __shared__ unsigned long long wres[2][4];
  const int b = blockIdx.x;
  const int tid = threadIdx.x;
  const int wave = tid >> 6, lane = tid & 63;
  const float* base = xyz + (size_t)b * NN * 3;
  for (int i = tid; i < NN; i += 256) {
    xs[i] = base[i*3+0]; ys[i] = base[i*3+1]; zs[i] = base[i*3+2];
  }
  __syncthreads();
  float px[16], py[16], pz[16], mind[16];
  #pragma unroll
  for (int j = 0; j < 16; ++j) {
    px[j] = xs[j*256 + tid];
    py[j] = ys[j*256 + tid];
    pz[j] = zs[j*256 + tid];
    mind[j] = 1e10f;
  }
  int far = 0;
  for (int it = 0; it < SS; ++it) {
    if (tid == 0) {
      out_xyz[(b*SS + it)*3 + 0] = xs[far];
      out_xyz[(b*SS + it)*3 + 1] = ys[far];
      out_xyz[(b*SS + it)*3 + 2] = zs[far];
    }
    const float cx = xs[far], cy = ys[far], cz = zs[far];
    float bv = -1.0f; int bj = 0;
    #pragma unroll
    for (int j = 0; j < 16; ++j) {
      float dx = __fsub_rn(px[j], cx);
      float dy = __fsub_rn(py[j], cy);
      float dz = __fsub_rn(pz[j], cz);
      float d  = __fadd_rn(__fadd_rn(__fmul_rn(dx,dx), __fmul_rn(dy,dy)), __fmul_rn(dz,dz));
      float md = fminf(mind[j], d);
      mind[j] = md;
      if (md > bv) { bv = md; bj = j; }
    }
    unsigned long long best = ((unsigned long long)__float_as_uint(bv) << 32)
                            | (unsigned int)(~(unsigned int)(bj*256 + tid));
    #define FPS_STEP(CTRL) { \
      unsigned int lo = (unsigned int)best, hi = (unsigned int)(best >> 32); \
      unsigned int lo2 = (unsigned int)__builtin_amdgcn_update_dpp((int)lo, (int)lo, CTRL, 0xf, 0xf, false); \
      unsigned int hi2 = (unsigned int)__builtin_amdgcn_update_dpp((int)hi, (int)hi, CTRL, 0xf, 0xf, false); \
      unsigned long long o = (((unsigned long long)hi2) << 32) | lo2; \
      if (o > best) best = o; }
    FPS_STEP(0x111) FPS_STEP(0x112) FPS_STEP(0x114) FPS_STEP(0x118)
    FPS_STEP(0x142) FPS_STEP(0x143)
    #undef FPS_STEP
    const int par = it & 1;
    if (lane == 63) wres[par][wave] = best;
    __syncthreads();
    unsigned long long g = wres[par][0];
    #pragma unroll
    for (int w = 1; w < 4; ++w) {
      unsigned long long o = wres[par][w];
      if (o > g) g = o;
    }
    far = (int)(~(unsigned int)g);
  }
}

// ---------------- kNN v2: batched ds_read_b128, 8 points/step ----------------
__global__ __launch_bounds__(64) void knn_kernel(
    const float* __restrict__ xyz, const float* __restrict__ new_xyz, int* __restrict__ knn_idx)
{
  __shared__ __align__(16) float tile[1536];   // 512 pts x 3, interleaved
  const int b = blockIdx.y;
  const int s = (blockIdx.x << 6) + threadIdx.x;
  const float cx = new_xyz[((b<<10)+s)*3+0];
  const float cy = new_xyz[((b<<10)+s)*3+1];
  const float cz = new_xyz[((b<<10)+s)*3+2];
  float td[16]; int ti[16];
  #pragma unroll
  for (int j = 0; j < 16; ++j) { td[j] = 3.4e38f; ti[j] = 0; }
  const float4* gbase = (const float4*)(xyz + (size_t)b*NN*3);
  for (int t0 = 0; t0 < NN; t0 += 512) {
    __syncthreads();
    {
      const float4* src = gbase + ((t0*3) >> 2);
      float4* dst = (float4*)tile;
      #pragma unroll
      for (int k = 0; k < 6; ++k) dst[threadIdx.x + k*64] = src[threadIdx.x + k*64];
    }
    __syncthreads();
    for (int i0 = 0; i0 < 512; i0 += 8) {
      const float4 v0 = *(const float4*)&tile[i0*3 +  0];
      const float4 v1 = *(const float4*)&tile[i0*3 +  4];
      const float4 v2 = *(const float4*)&tile[i0*3 +  8];
      const float4 v3 = *(const float4*)&tile[i0*3 + 12];
      const float4 v4 = *(const float4*)&tile[i0*3 + 16];
      const float4 v5 = *(const float4*)&tile[i0*3 + 20];
      float d[8];
      #define KDIST(slot, X, Y, Z) { \
        float dx = __fsub_rn(X, cx); \
        float dy = __fsub_rn(Y, cy); \
        float dz = __fsub_rn(Z, cz); \
        d[slot] = __fadd_rn(__fadd_rn(__fmul_rn(dx,dx), __fmul_rn(dy,dy)), __fmul_rn(dz,dz)); }
      KDIST(0, v0.x, v0.y, v0.z)
      KDIST(1, v0.w, v1.x, v1.y)
      KDIST(2, v1.z, v1.w, v2.x)
      KDIST(3, v2.y, v2.z, v2.w)
      KDIST(4, v3.x, v3.y, v3.z)
      KDIST(5, v3.w, v4.x, v4.y)
      KDIST(6, v4.z, v4.w, v5.x)
      KDIST(7, v5.y, v5.z, v5.w)
      #undef KDIST
      #pragma unroll
      for (int j = 0; j < 8; ++j) {
        if (d[j] < td[15]) {
          td[15] = d[j]; ti[15] = t0 + i0 + j;
          #pragma unroll
          for (int q = 15; q > 0; --q) {
            if (td[q] < td[q-1]) {
              float tf = td[q]; td[q] = td[q-1]; td[q-1] = tf;
              int   tt = ti[q]; ti[q] = ti[q-1]; ti[q-1] = tt;
            }
          }
        }
      }
    }
  }
  int* o = knn_idx + ((size_t)((b<<10)+s))*16;
  #pragma unroll
  for (int j = 0; j < 16; ++j) o[j] = ti[j];
}

// ---- helper: stage gathered feature tile into LDS ----
__device__ __forceinline__ void stage_features(
    unsigned short* Fs, const float* xyz, const float* points,
    const int* knn_idx, const float* new_xyz, int b, int by, int tid)
{
  const int rg = tid >> 2, cg = tid & 3;
  const int m = by*64 + rg;
  const int s = m >> 4, kk = m & 15;
  const int p = knn_idx[((b<<10)+s)*16 + kk];
  const float4* pb = (const float4*)(points + ((size_t)b*NN + p) * DD);
  unsigned short* row = Fs + rg*FP;
  #pragma unroll
  for (int i = 0; i < 8; ++i) {
    float4 v = pb[cg*8 + i];
    ushort4 u;
    u.x = f2bf(v.x); u.y = f2bf(v.y); u.z = f2bf(v.z); u.w = f2bf(v.w);
    *(ushort4*)&row[cg*32 + i*4] = u;
  }
  if (cg == 0) {
    float c3[3];
    c3[0] = xyz[((size_t)b*NN + p)*3+0] - new_xyz[((b<<10)+s)*3+0];
    c3[1] = xyz[((size_t)b*NN + p)*3+1] - new_xyz[((b<<10)+s)*3+1];
    c3[2] = xyz[((size_t)b*NN + p)*3+2] - new_xyz[((b<<10)+s)*3+2];
    #pragma unroll
    for (int k = 128; k < 160; k += 4) {
      ushort4 u;
      u.x = f2bf(k+0 < 131 ? c3[k-128+0] : 0.0f);
      u.y = f2bf(k+1 < 131 ? c3[k-128+1] : 0.0f);
      u.z = f2bf(k+2 < 131 ? c3[k-128+2] : 0.0f);
      u.w = f2bf(k+3 < 131 ? c3[k-128+3] : 0.0f);
      *(ushort4*)&row[k] = u;
    }
  }
}

// ---------------- pass A: y1 (MFMA) -> BN1 partials only ----------------
__global__ __launch_bounds__(256, 2) void gemm1_stats_kernel(
    const float* __restrict__ xyz, const float* __restrict__ points,
    const unsigned short* __restrict__ W1b, const float* __restrict__ bias1,
    const int* __restrict__ knn_idx, const float* __restrict__ new_xyz,
    float* __restrict__ Psum, float* __restrict__ Psq)
{
  __shared__ unsigned short Fs[64*FP];
  __shared__ unsigned short Ws[256*WP];
  __shared__ float RedS[1024];
  __shared__ float RedQ[1024];
  const int by = blockIdx.x, b = blockIdx.y;
  const int tid = threadIdx.x;
  const int wave = tid >> 6, lane = tid & 63;
  const int m15 = lane & 15, quad = lane >> 4;
  const int n0w = wave * 64;

  stage_features(Fs, xyz, points, knn_idx, new_xyz, b, by, tid);

  f32x4 acc[4][4];
  #pragma unroll
  for (int t = 0; t < 4; ++t)
    #pragma unroll
    for (int u = 0; u < 4; ++u) acc[t][u] = (f32x4){0.f,0.f,0.f,0.f};

  for (int kc = 0; kc < 5; ++kc) {
    const int k0 = kc * 32;
    __syncthreads();
    {
      const uint4* src = (const uint4*)(W1b + (size_t)tid*160 + k0);
      uint4* dst = (uint4*)(Ws + tid*WP);
      #pragma unroll
      for (int i = 0; i < 4; ++i) dst[i] = src[i];
    }
    __syncthreads();
    bf16x8 af[4], bfr[4];
    #pragma unroll
    for (int t = 0; t < 4; ++t) af[t]  = *(const bf16x8*)&Fs[(t*16 + m15)*FP + k0 + quad*8];
    #pragma unroll
    for (int u = 0; u < 4; ++u) bfr[u] = *(const bf16x8*)&Ws[(n0w + u*16 + m15)*WP + quad*8];
    #pragma unroll
    for (int t = 0; t < 4; ++t)
      #pragma unroll
      for (int u = 0; u < 4; ++u)
        acc[t][u] = __builtin_amdgcn_mfma_f32_16x16x32_bf16(af[t], bfr[u], acc[t][u], 0, 0, 0);
  }

  #pragma unroll
  for (int u = 0; u < 4; ++u) {
    const int n = n0w + u*16 + m15;
    const float bias = bias1[n];
    float ps = 0.f, pq = 0.f;
    #pragma unroll
    for (int t = 0; t < 4; ++t)
      #pragma unroll
      for (int r = 0; r < 4; ++r) {
        float y = acc[t][u][r] + bias;
        ps += y; pq += y*y;
      }
    RedS[n*4 + quad] = ps;
    RedQ[n*4 + quad] = pq;
  }
  __syncthreads();
  {
    const int n = tid;
    float4 s4 = *(const float4*)&RedS[n*4];
    float4 q4 = *(const float4*)&RedQ[n*4];
    const int row = b*256 + by;
    Psum[(size_t)n*4096 + row] = (s4.x + s4.y) + (s4.z + s4.w);
    Psq [(size_t)n*4096 + row] = (q4.x + q4.y) + (q4.z + q4.w);
  }
}

// ---------------- stats ----------------
__global__ __launch_bounds__(256) void stats_kernel(
    const float* __restrict__ Psum, const float* __restrict__ Psq,
    const float* __restrict__ gamma, const float* __restrict__ beta,
    float* __restrict__ scale, float* __restrict__ shift)
{
  __shared__ float sv[4], qv[4];
  const int c = blockIdx.x, tid = threadIdx.x;
  float s = 0.f, q = 0.f;
  for (int r = tid; r < 4096; r += 256) { s += Psum[(size_t)c*4096+r]; q += Psq[(size_t)c*4096+r]; }
  #pragma unroll
  for (int off = 32; off > 0; off >>= 1) { s += __shfl_down(s, off); q += __shfl_down(q, off); }
  if ((tid & 63) == 0) { sv[tid>>6] = s; qv[tid>>6] = q; }
  __syncthreads();
  if (tid == 0) {
    s = sv[0]+sv[1]+sv[2]+sv[3]; q = qv[0]+qv[1]+qv[2]+qv[3];
    const float count = 262144.0f;
    float mean = s / count;
    float var  = fmaxf(q / count - mean*mean, 0.0f);
    float inv  = 1.0f / sqrtf(var + 1e-5f);
    float sc   = gamma[c] * inv;
    scale[c] = sc;
    shift[c] = beta[c] - mean * sc;
  }
}

// ---------------- fused: y1 (MFMA) -> bn1+relu -> y2 (MFMA) -> BN2 partials + max/min ----------------
__global__ __launch_bounds__(256, 2) void fused2_kernel(
    const float* __restrict__ xyz, const float* __restrict__ points,
    const unsigned short* __restrict__ W1b, const float* __restrict__ bias1,
    const int* __restrict__ knn_idx, const float* __restrict__ new_xyz,
    const float* __restrict__ sc1v, const float* __restrict__ sh1v,
    const unsigned short* __restrict__ W2b, const float* __restrict__ bias2,
    float* __restrict__ maxv, float* __restrict__ minv,
    float* __restrict__ Psum, float* __restrict__ Psq)
{
  __shared__ char smem[58368];
  unsigned short* As_  = (unsigned short*)smem;
  unsigned short* Fs   = (unsigned short*)smem;
  unsigned short* Ws   = (unsigned short*)(smem + 33792);
  float* RedS  = (float*)(smem + 33792);
  float* RedQ  = (float*)(smem + 37888);
  float* MMBuf = (float*)(smem + 41984);

  const int by = blockIdx.x, b = blockIdx.y;
  const int tid = threadIdx.x;
  const int wave = tid >> 6, lane = tid & 63;
  const int m15 = lane & 15, quad = lane >> 4;
  const int n0w = wave * 64;

  stage_features(Fs, xyz, points, knn_idx, new_xyz, b, by, tid);

  f32x4 acc[4][4];
  #pragma unroll
  for (int t = 0; t < 4; ++t)
    #pragma unroll
    for (int u = 0; u < 4; ++u) acc[t][u] = (f32x4){0.f,0.f,0.f,0.f};

  for (int kc = 0; kc < 5; ++kc) {
    const int k0 = kc * 32;
    __syncthreads();
    {
      const uint4* src = (const uint4*)(W1b + (size_t)tid*160 + k0);
      uint4* dst = (uint4*)(Ws + tid*WP);
      #pragma unroll
      for (int i = 0; i < 4; ++i) dst[i] = src[i];
    }
    __syncthreads();
    bf16x8 af[4], bfr[4];
    #pragma unroll
    for (int t = 0; t < 4; ++t) af[t]  = *(const bf16x8*)&Fs[(t*16 + m15)*FP + k0 + quad*8];
    #pragma unroll
    for (int u = 0; u < 4; ++u) bfr[u] = *(const bf16x8*)&Ws[(n0w + u*16 + m15)*WP + quad*8];
    #pragma unroll
    for (int t = 0; t < 4; ++t)
      #pragma unroll
      for (int u = 0; u < 4; ++u)
        acc[t][u] = __builtin_amdgcn_mfma_f32_16x16x32_bf16(af[t], bfr[u], acc[t][u], 0, 0, 0);
  }

  __syncthreads();

  #pragma unroll
  for (int u = 0; u < 4; ++u) {
    const int n = n0w + u*16 + m15;
    const float bias = bias1[n], sc = sc1v[n], sh = sh1v[n];
    #pragma unroll
    for (int t = 0; t < 4; ++t)
      #pragma unroll
      for (int r = 0; r < 4; ++r) {
        float a = fmaxf((acc[t][u][r] + bias)*sc + sh, 0.0f);
        As_[(t*16 + quad*4 + r)*AP + n] = f2bf(a);
      }
  }

  #pragma unroll
  for (int t = 0; t < 4; ++t)
    #pragma unroll
    for (int u = 0; u < 4; ++u) acc[t][u] = (f32x4){0.f,0.f,0.f,0.f};

  for (int kc = 0; kc < 8; ++kc) {
    const int k0 = kc * 32;
    __syncthreads();
    {
      const uint4* src = (const uint4*)(W2b + (size_t)tid*256 + k0);
      uint4* dst = (uint4*)(Ws + tid*WP);
      #pragma unroll
      for (int i = 0; i < 4; ++i) dst[i] = src[i];
    }
    __syncthreads();
    bf16x8 af[4], bfr[4];
    #pragma unroll
    for (int t = 0; t < 4; ++t) af[t]  = *(const bf16x8*)&As_[(t*16 + m15)*AP + k0 + quad*8];
    #pragma unroll
    for (int u = 0; u < 4; ++u) bfr[u] = *(const bf16x8*)&Ws[(n0w + u*16 + m15)*WP + quad*8];
    #pragma unroll
    for (int t = 0; t < 4; ++t)
      #pragma unroll
      for (int u = 0; u < 4; ++u)
        acc[t][u] = __builtin_amdgcn_mfma_f32_16x16x32_bf16(af[t], bfr[u], acc[t][u], 0, 0, 0);
  }

  __syncthreads();

  float mxv[4][4], mnv[4][4];
  #pragma unroll
  for (int u = 0; u < 4; ++u) {
    const int n = n0w + u*16 + m15;
    const float bias = bias2[n];
    float ps = 0.f, pq = 0.f;
    #pragma unroll
    for (int t = 0; t < 4; ++t) {
      float y0 = acc[t][u][0] + bias, y1 = acc[t][u][1] + bias;
      float y2 = acc[t][u][2] + bias, y3 = acc[t][u][3] + bias;
      ps += ((y0 + y1) + (y2 + y3));
      pq += ((y0*y0 + y1*y1) + (y2*y2 + y3*y3));
      mxv[t][u] = fmaxf(fmaxf(y0, y1), fmaxf(y2, y3));
      mnv[t][u] = fminf(fminf(y0, y1), fminf(y2, y3));
    }
    RedS[n*4 + quad] = ps;
    RedQ[n*4 + quad] = pq;
    #pragma unroll
    for (int t = 0; t < 4; ++t) MMBuf[(t*256 + n)*4 + quad] = mxv[t][u];
  }
  __syncthreads();
  {
    const int n = tid;
    float4 s4 = *(const float4*)&RedS[n*4];
    float4 q4 = *(const float4*)&RedQ[n*4];
    const int row = b*256 + by;
    Psum[(size_t)n*4096 + row] = (s4.x + s4.y) + (s4.z + s4.w);
    Psq [(size_t)n*4096 + row] = (q4.x + q4.y) + (q4.z + q4.w);
    #pragma unroll
    for (int j = 0; j < 4; ++j) {
      float4 m4 = *(const float4*)&MMBuf[(j*256 + n)*4];
      float v = fmaxf(fmaxf(m4.x, m4.y), fmaxf(m4.z, m4.w));
      maxv[((size_t)((b<<10) + by*4 + j))*C1 + n] = v;
    }
  }
  __syncthreads();
  #pragma unroll
  for (int u = 0; u < 4; ++u) {
    const int n = n0w + u*16 + m15;
    #pragma unroll
    for (int t = 0; t < 4; ++t) MMBuf[(t*256 + n)*4 + quad] = mnv[t][u];
  }
  __syncthreads();
  {
    const int n = tid;
    #pragma unroll
    for (int j = 0; j < 4; ++j) {
      float4 m4 = *(const float4*)&MMBuf[(j*256 + n)*4];
      float v = fminf(fminf(m4.x, m4.y), fminf(m4.z, m4.w));
      minv[((size_t)((b<<10) + by*4 + j))*C1 + n] = v;
    }
  }
}

// ---------------- final ----------------
__global__ __launch_bounds__(256) void final_kernel(
    const float* __restrict__ maxv, const float* __restrict__ minv,
    const float* __restrict__ scale2, const float* __restrict__ shift2,
    float* __restrict__ out)
{
  const int bs = blockIdx.x;
  const int n  = threadIdx.x;
  const float sc = scale2[n], sh = shift2[n];
  const size_t idx = (size_t)bs * C1 + n;
  const float sel = (sc >= 0.0f) ? maxv[idx] : minv[idx];
  out[(size_t)BB*SS*3 + idx] = fmaxf(sc*sel + sh, 0.0f);
}

extern "C" void kernel_launch(void* const* d_in, const int* in_sizes, int n_in,
                              void* d_out, int out_size, void* d_ws, size_t ws_size,
                              hipStream_t stream) {
  const float* xyz    = (const float*)d_in[0];
  const float* points = (const float*)d_in[1];
  const float* W1     = (const float*)d_in[2];
  const float* b1     = (const float*)d_in[3];
  const float* g1     = (const float*)d_in[4];
  const float* bt1    = (const float*)d_in[5];
  const float* W2     = (const float*)d_in[6];
  const float* b2     = (const float*)d_in[7];
  const float* g2     = (const float*)d_in[8];
  const float* bt2    = (const float*)d_in[9];
  float* out = (float*)d_out;
  char* ws = (char*)d_ws;

  int*   knn_idx = (int*)(ws + 0);
  float* Ps      = (float*)(ws + 1048576ULL);
  float* Pq      = (float*)(ws + 5242880ULL);
  float* sc1     = (float*)(ws + 9437184ULL);
  float* sh1     = (float*)(ws + 9438208ULL);
  float* sc2     = (float*)(ws + 9439232ULL);
  float* sh2     = (float*)(ws + 9440256ULL);
  float* maxv    = (float*)(ws + 9441280ULL);
  float* minv    = (float*)(ws + 26218496ULL);
  unsigned short* W1b = (unsigned short*)(ws + 42995712ULL);
  unsigned short* W2b = (unsigned short*)(ws + 43077632ULL);

  float* new_xyz = out;

  convert_kernel<<<256, 256, 0, stream>>>(W1, W2, W1b, W2b);
  fps_kernel<<<BB, 256, 0, stream>>>(xyz, new_xyz);
  knn_kernel<<<dim3(16, BB), 64, 0, stream>>>(xyz, new_xyz, knn_idx);
  gemm1_stats_kernel<<<dim3(256, BB), 256, 0, stream>>>(xyz, points, W1b, b1, knn_idx, new_xyz, Ps, Pq);
  stats_kernel<<<256, 256, 0, stream>>>(Ps, Pq, g1, bt1, sc1, sh1);
  fused2_kernel<<<dim3(256, BB), 256, 0, stream>>>(xyz, points, W1b, b1, knn_idx, new_xyz,
                                                   sc1, sh1, W2b, b2, maxv, minv, Ps, Pq);
  stats_kernel<<<256, 256, 0, stream>>>(Ps, Pq, g2, bt2, sc2, sh2);
  final_kernel<<<BB*SS, 256, 0, stream>>>(maxv, minv, sc2, sh2, out);
}